// Round 8
// baseline (328.613 us; speedup 1.0000x reference)
//
#include <hip/hip_runtime.h>

// ConvRecLayer: dynamic conv (H=16, K=15, causal) + LayerNorm + FFN(relu) + residual
// T=1024 B=8 C=1024 F=4096. Inputs/outputs fp32 (per reference); internal compute bf16 MFMA.

#define T_DIM 1024
#define B_DIM 8
#define C_DIM 1024
#define F_DIM 4096
#define H_DIM 16
#define K_TAP 15
#define TB (T_DIM * B_DIM)   // 8192 rows

typedef __attribute__((ext_vector_type(8))) short short8;
typedef __attribute__((ext_vector_type(4))) float f32x4;

__device__ __forceinline__ float bf2f(unsigned short u) {
    union { unsigned int i; float f; } v; v.i = ((unsigned int)u) << 16; return v.f;
}
__device__ __forceinline__ unsigned short f2bf(float f) {
    union { float f; unsigned int i; } v; v.f = f;
    unsigned int r = v.i + 0x7fffu + ((v.i >> 16) & 1u);  // RNE
    return (unsigned short)(r >> 16);
}

// async global->LDS DMA, 16B per lane: lane i reads gptr(lane) -> ldsbase + i*16
__device__ __forceinline__ void async_copy16(const void* gptr, void* lptr) {
    __builtin_amdgcn_global_load_lds(
        (const __attribute__((address_space(1))) void*)gptr,
        (__attribute__((address_space(3))) void*)lptr, 16, 0, 0);
}

// ---------------------------------------------------------------------------
// prep: fused fp32->bf16 convert of x + three fp32->bf16 transposes.
// Grid partition (256 threads each):
//   [0, 8192)          cvt x -> xb (4 elems/thread)
//   [8192, 12288)      fc1_w (C x F) -> fc1T (F x C)
//   [12288, 16384)     fc2_w (F x C) -> fc2T (C x F)
//   [16384, 16640)     w_lin (C x 240) -> wlinT (256 x C), rows 240..255 zero
// ---------------------------------------------------------------------------
__global__ __launch_bounds__(256)
void prep(const float* __restrict__ x, unsigned short* __restrict__ xb,
          const float* __restrict__ fc1_w, unsigned short* __restrict__ fc1T,
          const float* __restrict__ fc2_w, unsigned short* __restrict__ fc2T,
          const float* __restrict__ w_lin, unsigned short* __restrict__ wlinT) {
    const int bid = blockIdx.x;
    const int tid = threadIdx.x;
    if (bid < 8192) {
        int i = (bid * 256 + tid) * 4;
        float4 v = *(const float4*)(x + i);
        uint2 o;
        o.x = (unsigned int)f2bf(v.x) | ((unsigned int)f2bf(v.y) << 16);
        o.y = (unsigned int)f2bf(v.z) | ((unsigned int)f2bf(v.w) << 16);
        *(uint2*)(xb + i) = o;
        return;
    }
    // transpose path
    const float* in; unsigned short* out; int R, Cin, c0, r0;
    if (bid < 12288) {
        int idx = bid - 8192;                 // grid (128, 32)
        in = fc1_w; out = fc1T; R = C_DIM; Cin = F_DIM;
        c0 = (idx & 127) * 32; r0 = (idx >> 7) * 32;
    } else if (bid < 16384) {
        int idx = bid - 12288;                // grid (32, 128)
        in = fc2_w; out = fc2T; R = F_DIM; Cin = C_DIM;
        c0 = (idx & 31) * 32; r0 = (idx >> 5) * 32;
    } else {
        int idx = bid - 16384;                // grid (8, 32)
        in = w_lin; out = wlinT; R = C_DIM; Cin = 240;
        c0 = (idx & 7) * 32; r0 = (idx >> 3) * 32;
    }
    __shared__ unsigned short tile[32][33];
    const int xx = tid & 31, yy = tid >> 5;   // 32 x 8
#pragma unroll
    for (int j = 0; j < 4; j++) {
        int r = r0 + yy + j * 8, c = c0 + xx;
        unsigned short v = 0;
        if (c < Cin) v = f2bf(in[(size_t)r * Cin + c]);
        tile[yy + j * 8][xx] = v;
    }
    __syncthreads();
#pragma unroll
    for (int j = 0; j < 4; j++) {
        out[(size_t)(c0 + yy + j * 8) * R + (r0 + xx)] = tile[xx][yy + j * 8];
    }
}

// ---------------------------------------------------------------------------
// gemm_bt: C[M x N] = A[M x K] @ Bt[N x K]^T  (bf16 in, fp32 acc)
// 128x128 block tile, 4 waves each computing 64x64 via 4x4 MFMA 16x16x32 tiles.
// BK=64 K-loop (32 MFMA/barrier), global_load_lds width=16 into DOUBLE-
// BUFFERED LDS (64 KiB, 2 blocks/CU), ONE __syncthreads per iteration
// (round-4/7 proven; explicit vmcnt pipelining regressed in round 5).
// LDS tile [128 rows][64 k]: 16B chunk c of row r stored at slot c ^ (r&7)
// (swizzle on the GLOBAL address side; DMA LDS dest is lane-contiguous).
// Fragment ds_read_b128s verified conflict-free (SQ_LDS_BANK_CONFLICT = 0).
// SWAP=1 puts the m-tile on blockIdx.x so the 8 n-tile blocks sharing an
// A(m)-tile land on the same XCD -> L2-served reuse (fc2: FETCH 285->81 MB).
// MODE 1: bf16 out = relu(acc + bias[n])
// MODE 2: fp32 out = acc + bias[n] + resid[m][n]   (resid bf16)
// Requires M%128==0, N%128==0, K%64==0, K >= 128.
// ---------------------------------------------------------------------------
template <int MODE, int SWAP>
__global__ __launch_bounds__(256)
void gemm_bt(const unsigned short* __restrict__ A,
             const unsigned short* __restrict__ Bt,
             void* __restrict__ Cout_v,
             int M, int N, int K,
             const float* __restrict__ bias,
             const unsigned short* __restrict__ resid) {
    __shared__ __align__(16) unsigned short As[2][128 * 64];
    __shared__ __align__(16) unsigned short Bs[2][128 * 64];

    const int tid = threadIdx.x;
    const int m0 = (SWAP ? blockIdx.x : blockIdx.y) * 128;
    const int n0 = (SWAP ? blockIdx.y : blockIdx.x) * 128;
    const int wave = tid >> 6, lane = tid & 63;
    const int quad = lane >> 4, l16 = lane & 15;
    const int wm = (wave >> 1) * 64;  // wave row offset in tile
    const int wn = (wave & 1) * 64;   // wave col offset in tile

    f32x4 acc[4][4];
#pragma unroll
    for (int i = 0; i < 4; i++)
#pragma unroll
        for (int j = 0; j < 4; j++) acc[i][j] = (f32x4){0.f, 0.f, 0.f, 0.f};

    // ---- DMA staging addresses -------------------------------------------
    // wave w stages rows [w*32, w*32+32) of A and B as 4 issues of 8 rows
    // each per operand. Lane i covers (row = i>>3, stored slot = i&7); the
    // global chunk it fetches is (i&7) ^ ((i>>3)&7).
    const int rsub = lane >> 3;                   // 0..7
    const int gch = (lane & 7) ^ rsub;            // swizzled global chunk
    const unsigned short* gA = A + (size_t)(m0 + wave * 32 + rsub) * K + gch * 8;
    const unsigned short* gB = Bt + (size_t)(n0 + wave * 32 + rsub) * K + gch * 8;
    unsigned short* lA[2] = {&As[0][wave * 32 * 64], &As[1][wave * 32 * 64]};
    unsigned short* lB[2] = {&Bs[0][wave * 32 * 64], &Bs[1][wave * 32 * 64]};

    // prologue: stage tile 0 into buffer 0
#pragma unroll
    for (int j = 0; j < 4; j++) {
        async_copy16(gA + (size_t)j * 8 * K, lA[0] + j * 8 * 64);
        async_copy16(gB + (size_t)j * 8 * K, lB[0] + j * 8 * 64);
    }

    const int swz = l16 & 7;                      // fragment-read swizzle
    int buf = 0;
    for (int k0 = 0; k0 < K; k0 += 64) {
        __syncthreads();   // drains own-wave DMA (tile k) + all waves' reads of buf^1

        const int nk = k0 + 64;
        if (nk < K) {      // prefetch tile k+1 into the other buffer
            const int nb = buf ^ 1;
#pragma unroll
            for (int j = 0; j < 4; j++) {
                async_copy16(gA + nk + (size_t)j * 8 * K, lA[nb] + j * 8 * 64);
                async_copy16(gB + nk + (size_t)j * 8 * K, lB[nb] + j * 8 * 64);
            }
        }

        short8 af[2][4], bfr[2][4];
#pragma unroll
        for (int kk = 0; kk < 2; kk++) {
            const int c = kk * 4 + quad;          // global chunk for this kk
#pragma unroll
            for (int i = 0; i < 4; i++) {
                af[kk][i]  = *(const short8*)(&As[buf][(wm + i * 16 + l16) * 64 + (c ^ swz) * 8]);
                bfr[kk][i] = *(const short8*)(&Bs[buf][(wn + i * 16 + l16) * 64 + (c ^ swz) * 8]);
            }
        }
#pragma unroll
        for (int kk = 0; kk < 2; kk++)
#pragma unroll
            for (int mi = 0; mi < 4; mi++)
#pragma unroll
                for (int nj = 0; nj < 4; nj++)
                    acc[mi][nj] = __builtin_amdgcn_mfma_f32_16x16x32_bf16(
                        af[kk][mi], bfr[kk][nj], acc[mi][nj], 0, 0, 0);
        buf ^= 1;
    }

    // epilogue: lane holds D[row=quad*4+i][col=l16] per 16x16 tile
    const int crow0 = m0 + wm + quad * 4;
    const int ccol0 = n0 + wn + l16;
    if (MODE == 1) {
        unsigned short* Cb = (unsigned short*)Cout_v;
        float bv[4];
#pragma unroll
        for (int nj = 0; nj < 4; nj++) bv[nj] = bias[ccol0 + nj * 16];
#pragma unroll
        for (int mi = 0; mi < 4; mi++)
#pragma unroll
            for (int i = 0; i < 4; i++) {
                int rr = crow0 + mi * 16 + i;
#pragma unroll
                for (int nj = 0; nj < 4; nj++) {
                    float v = fmaxf(acc[mi][nj][i] + bv[nj], 0.f);
                    Cb[(size_t)rr * N + ccol0 + nj * 16] = f2bf(v);
                }
            }
    } else {  // MODE 2
        float* Cf = (float*)Cout_v;
        float bv[4];
#pragma unroll
        for (int nj = 0; nj < 4; nj++) bv[nj] = bias[ccol0 + nj * 16];
#pragma unroll
        for (int mi = 0; mi < 4; mi++)
#pragma unroll
            for (int i = 0; i < 4; i++) {
                int rr = crow0 + mi * 16 + i;
#pragma unroll
                for (int nj = 0; nj < 4; nj++) {
                    float v = acc[mi][nj][i] + bv[nj]
                            + bf2f(resid[(size_t)rr * N + ccol0 + nj * 16]);
                    Cf[(size_t)rr * N + ccol0 + nj * 16] = v;
                }
            }
    }
}

// ---------------------------------------------------------------------------
// conv_fused: logits-GEMM + tap-softmax + causal dynamic conv + LayerNorm,
// 16 t-rows per block (512 blocks). Phases:
//  0) stage 30 xb rows (t0-14 .. t0+15) in LDS, padded stride 1032 elems
//     (2064 B == 4 dwords mod 32 banks -> phase-1/3 reads are 2-way = free).
//  1) wscore(16x240) = X(16x1024) @ wlinT^T via MFMA 16x16x32: A-frag rows
//     are exactly the 16 t-rows (m = lane&15); B-frags read directly from
//     global wlinT (0.5 MB, L2-resident across all 512 blocks). Full K=1024
//     in-block -- no split-K partials, no 32MBx2 HBM round-trip.
//  2) softmax: 256 threads = 16 rows x 16 heads, in-place in LDS.
//  3) conv + LN (round-6 verified): wave handles 4 rows, lane owns 16
//     consecutive channels (head = lane>>2), wave-local shuffle reduction.
// ---------------------------------------------------------------------------
#define XSP 1032   // padded LDS row stride (bf16 elems)
__global__ __launch_bounds__(256)
void conv_fused(const unsigned short* __restrict__ xb,
                const unsigned short* __restrict__ wlinT,
                const float* __restrict__ b_lin,
                const float* __restrict__ ln_g,
                const float* __restrict__ ln_b,
                unsigned short* __restrict__ y) {
    __shared__ __align__(16) unsigned short xs[30 * XSP];   // 60.5 KiB
    __shared__ float sc[16 * 256];                          // 16 KiB (wscore -> wconv)
    const int blk = blockIdx.x;          // 0..511
    const int b = blk & 7;
    const int t0 = (blk >> 3) * 16;
    const int tid = threadIdx.x;

    // phase 0: stage 30 x-rows, 8B per thread per row
#pragma unroll
    for (int j = 0; j < 30; j++) {
        int t = t0 + j - 14;
        uint2 val = make_uint2(0u, 0u);
        if (t >= 0)
            val = *(const uint2*)(xb + ((size_t)t * B_DIM + b) * C_DIM + tid * 4);
        *(uint2*)(&xs[j * XSP + tid * 4]) = val;
    }
    __syncthreads();

    const int wave = tid >> 6, lane = tid & 63;
    const int quad = lane >> 4, l16 = lane & 15;

    // phase 1: logits. wave w computes n-tiles 4w..4w+3 (n = ntile*16+l16).
    f32x4 acc[4];
#pragma unroll
    for (int nt = 0; nt < 4; nt++) acc[nt] = (f32x4){0.f, 0.f, 0.f, 0.f};
    for (int ki = 0; ki < 32; ki++) {
        short8 a = *(const short8*)(&xs[(14 + l16) * XSP + ki * 32 + quad * 8]);
#pragma unroll
        for (int nt = 0; nt < 4; nt++) {
            int n = (wave * 4 + nt) * 16 + l16;
            short8 bf = *(const short8*)(wlinT + (size_t)n * C_DIM + ki * 32 + quad * 8);
            acc[nt] = __builtin_amdgcn_mfma_f32_16x16x32_bf16(a, bf, acc[nt], 0, 0, 0);
        }
    }
    // scatter C-layout (row = quad*4+i, col = l16) into sc[row][n]
#pragma unroll
    for (int nt = 0; nt < 4; nt++)
#pragma unroll
        for (int i = 0; i < 4; i++)
            sc[(quad * 4 + i) * 256 + (wave * 4 + nt) * 16 + l16] = acc[nt][i];
    __syncthreads();

    // phase 2: per-(row, head) softmax over 15 taps, in place
    {
        const int row = tid >> 4, hh = tid & 15;
        float* p = &sc[row * 256 + hh * K_TAP];
        float v[K_TAP], mx = -1e30f;
#pragma unroll
        for (int k = 0; k < K_TAP; k++) {
            v[k] = p[k] + b_lin[hh * K_TAP + k];
            mx = fmaxf(mx, v[k]);
        }
        float s = 0.f;
#pragma unroll
        for (int k = 0; k < K_TAP; k++) { v[k] = __expf(v[k] - mx); s += v[k]; }
        float inv = 1.0f / s;
#pragma unroll
        for (int k = 0; k < K_TAP; k++) p[k] = v[k] * inv;
    }
    __syncthreads();

    // phase 3: conv + LN. wave handles rows wave, wave+4, wave+8, wave+12.
    const int ch0 = lane * 16;
    const int h = lane >> 2;             // head index, constant over lane's 16 ch
    for (int rj = wave; rj < 16; rj += 4) {
        float o[16];
#pragma unroll
        for (int i = 0; i < 16; i++) o[i] = 0.f;
#pragma unroll
        for (int k = 0; k < K_TAP; k++) {
            float w = sc[rj * 256 + h * K_TAP + k];
            const unsigned short* xr = &xs[(rj + k) * XSP + ch0];
            uint4 p0 = *(const uint4*)(xr);
            uint4 p1 = *(const uint4*)(xr + 8);
            unsigned int uu[8] = {p0.x, p0.y, p0.z, p0.w, p1.x, p1.y, p1.z, p1.w};
#pragma unroll
            for (int q = 0; q < 8; q++) {
                o[2 * q]     += w * bf2f((unsigned short)(uu[q] & 0xffff));
                o[2 * q + 1] += w * bf2f((unsigned short)(uu[q] >> 16));
            }
        }
        float s = 0.f, s2 = 0.f;
#pragma unroll
        for (int i = 0; i < 16; i++) { s += o[i]; s2 += o[i] * o[i]; }
#pragma unroll
        for (int off = 32; off > 0; off >>= 1) {
            s  += __shfl_xor(s, off, 64);
            s2 += __shfl_xor(s2, off, 64);
        }
        float mu = s * (1.0f / C_DIM);
        float var = s2 * (1.0f / C_DIM) - mu * mu;
        float rs = rsqrtf(var + 1e-5f);

        unsigned short o16[16];
#pragma unroll
        for (int i = 0; i < 16; i++)
            o16[i] = f2bf((o[i] - mu) * rs * ln_g[ch0 + i] + ln_b[ch0 + i]);
        uint4 w0, w1;
        w0.x = (unsigned int)o16[0]  | ((unsigned int)o16[1]  << 16);
        w0.y = (unsigned int)o16[2]  | ((unsigned int)o16[3]  << 16);
        w0.z = (unsigned int)o16[4]  | ((unsigned int)o16[5]  << 16);
        w0.w = (unsigned int)o16[6]  | ((unsigned int)o16[7]  << 16);
        w1.x = (unsigned int)o16[8]  | ((unsigned int)o16[9]  << 16);
        w1.y = (unsigned int)o16[10] | ((unsigned int)o16[11] << 16);
        w1.z = (unsigned int)o16[12] | ((unsigned int)o16[13] << 16);
        w1.w = (unsigned int)o16[14] | ((unsigned int)o16[15] << 16);
        unsigned short* yr = y + ((size_t)(t0 + rj) * B_DIM + b) * C_DIM + ch0;
        *(uint4*)(yr) = w0;
        *(uint4*)(yr + 8) = w1;
    }
}

// ---------------------------------------------------------------------------
extern "C" void kernel_launch(void* const* d_in, const int* in_sizes, int n_in,
                              void* d_out, int out_size, void* d_ws, size_t ws_size,
                              hipStream_t stream) {
    const float* x     = (const float*)d_in[0];
    const float* w_lin = (const float*)d_in[1];
    const float* b_lin = (const float*)d_in[2];
    const float* ln_g  = (const float*)d_in[3];
    const float* ln_b  = (const float*)d_in[4];
    const float* fc1_w = (const float*)d_in[5];
    const float* fc1_b = (const float*)d_in[6];
    const float* fc2_w = (const float*)d_in[7];
    const float* fc2_b = (const float*)d_in[8];
    float* out = (float*)d_out;

    // workspace layout (bytes); total ~112.5 MiB
    char* ws = (char*)d_ws;
    unsigned short* xb    = (unsigned short*)(ws);                      // TB x C   16 MiB
    unsigned short* fc1T  = (unsigned short*)(ws + 16777216);           // F x C     8 MiB
    unsigned short* fc2T  = (unsigned short*)(ws + 25165824);           // C x F     8 MiB
    unsigned short* wlinT = (unsigned short*)(ws + 33554432);           // 256 x C   0.5 MiB
    unsigned short* y     = (unsigned short*)(ws + 34078720);           // TB x C   16 MiB
    unsigned short* h     = (unsigned short*)(ws + 50855936);           // TB x F   64 MiB

    // fused convert + transposes (1 launch)
    prep<<<16640, 256, 0, stream>>>(x, xb, fc1_w, fc1T, fc2_w, fc2T, w_lin, wlinT);

    // fused logits-GEMM + softmax + dynamic conv + LayerNorm -> y (bf16)
    conv_fused<<<TB / 16, 256, 0, stream>>>(xb, wlinT, b_lin, ln_g, ln_b, y);

    // h = relu(y @ fc1_w + fc1_b)  (bf16)
    gemm_bt<1, 0><<<dim3(F_DIM / 128, TB / 128), 256, 0, stream>>>(
        y, fc1T, (void*)h, TB, F_DIM, C_DIM, fc1_b, nullptr);

    // out = h @ fc2_w + fc2_b + y  (fp32); m-tile on x for same-XCD h reuse
    gemm_bt<2, 1><<<dim3(TB / 128, C_DIM / 128), 256, 0, stream>>>(
        h, fc2T, (void*)out, TB, C_DIM, F_DIM, fc2_b, y);
}

// Round 9
// 300.645 us; speedup vs baseline: 1.0930x; 1.0930x over previous
//
#include <hip/hip_runtime.h>

// ConvRecLayer: dynamic conv (H=16, K=15, causal) + LayerNorm + FFN(relu) + residual
// T=1024 B=8 C=1024 F=4096. Inputs/outputs fp32 (per reference); internal compute bf16 MFMA.

#define T_DIM 1024
#define B_DIM 8
#define C_DIM 1024
#define F_DIM 4096
#define H_DIM 16
#define K_TAP 15
#define TB (T_DIM * B_DIM)   // 8192 rows

typedef __attribute__((ext_vector_type(8))) short short8;
typedef __attribute__((ext_vector_type(4))) float f32x4;

__device__ __forceinline__ float bf2f(unsigned short u) {
    union { unsigned int i; float f; } v; v.i = ((unsigned int)u) << 16; return v.f;
}
__device__ __forceinline__ unsigned short f2bf(float f) {
    union { float f; unsigned int i; } v; v.f = f;
    unsigned int r = v.i + 0x7fffu + ((v.i >> 16) & 1u);  // RNE
    return (unsigned short)(r >> 16);
}

// async global->LDS DMA, 16B per lane: lane i reads gptr(lane) -> ldsbase + i*16
__device__ __forceinline__ void async_copy16(const void* gptr, void* lptr) {
    __builtin_amdgcn_global_load_lds(
        (const __attribute__((address_space(1))) void*)gptr,
        (__attribute__((address_space(3))) void*)lptr, 16, 0, 0);
}

// ---------------------------------------------------------------------------
// prep: fused fp32->bf16 convert of x + three fp32->bf16 transposes.
// Grid partition (256 threads each):
//   [0, 8192)          cvt x -> xb (4 elems/thread)
//   [8192, 12288)      fc1_w (C x F) -> fc1T (F x C)
//   [12288, 16384)     fc2_w (F x C) -> fc2T (C x F)
//   [16384, 16640)     w_lin (C x 240) -> wlinT (256 x C), rows 240..255 zero
// ---------------------------------------------------------------------------
__global__ __launch_bounds__(256)
void prep(const float* __restrict__ x, unsigned short* __restrict__ xb,
          const float* __restrict__ fc1_w, unsigned short* __restrict__ fc1T,
          const float* __restrict__ fc2_w, unsigned short* __restrict__ fc2T,
          const float* __restrict__ w_lin, unsigned short* __restrict__ wlinT) {
    const int bid = blockIdx.x;
    const int tid = threadIdx.x;
    if (bid < 8192) {
        int i = (bid * 256 + tid) * 4;
        float4 v = *(const float4*)(x + i);
        uint2 o;
        o.x = (unsigned int)f2bf(v.x) | ((unsigned int)f2bf(v.y) << 16);
        o.y = (unsigned int)f2bf(v.z) | ((unsigned int)f2bf(v.w) << 16);
        *(uint2*)(xb + i) = o;
        return;
    }
    // transpose path
    const float* in; unsigned short* out; int R, Cin, c0, r0;
    if (bid < 12288) {
        int idx = bid - 8192;                 // grid (128, 32)
        in = fc1_w; out = fc1T; R = C_DIM; Cin = F_DIM;
        c0 = (idx & 127) * 32; r0 = (idx >> 7) * 32;
    } else if (bid < 16384) {
        int idx = bid - 12288;                // grid (32, 128)
        in = fc2_w; out = fc2T; R = F_DIM; Cin = C_DIM;
        c0 = (idx & 31) * 32; r0 = (idx >> 5) * 32;
    } else {
        int idx = bid - 16384;                // grid (8, 32)
        in = w_lin; out = wlinT; R = C_DIM; Cin = 240;
        c0 = (idx & 7) * 32; r0 = (idx >> 3) * 32;
    }
    __shared__ unsigned short tile[32][33];
    const int xx = tid & 31, yy = tid >> 5;   // 32 x 8
#pragma unroll
    for (int j = 0; j < 4; j++) {
        int r = r0 + yy + j * 8, c = c0 + xx;
        unsigned short v = 0;
        if (c < Cin) v = f2bf(in[(size_t)r * Cin + c]);
        tile[yy + j * 8][xx] = v;
    }
    __syncthreads();
#pragma unroll
    for (int j = 0; j < 4; j++) {
        out[(size_t)(c0 + yy + j * 8) * R + (r0 + xx)] = tile[xx][yy + j * 8];
    }
}

// ---------------------------------------------------------------------------
// gemm_bt: C[M x N] = A[M x K] @ Bt[N x K]^T  (bf16 in, fp32 acc)
// 128x128 block tile, 4 waves each computing 64x64 via 4x4 MFMA 16x16x32 tiles.
// BK=64 K-loop (32 MFMA/barrier), global_load_lds width=16 into DOUBLE-
// BUFFERED LDS (64 KiB, 2 blocks/CU), ONE __syncthreads per iteration
// (round-4/7 proven; explicit vmcnt pipelining regressed in round 5).
// LDS tile [128 rows][64 k]: 16B chunk c of row r stored at slot c ^ (r&7)
// (swizzle on the GLOBAL address side; DMA LDS dest is lane-contiguous).
// Fragment ds_read_b128s verified conflict-free (SQ_LDS_BANK_CONFLICT = 0).
// SWAP=1 puts the m-tile on blockIdx.x so the 8 n-tile blocks sharing an
// A(m)-tile land on the same XCD -> L2-served reuse (fc2: FETCH 285->81 MB,
// = exact one-pass traffic floor).
// Split-K via gridDim.z (MODE 3 writes partial to Cout + z*M*N).
// MODE 1: bf16 out = relu(acc + bias[n])
// MODE 2: fp32 out = acc + bias[n] + resid[m][n]   (resid bf16)
// MODE 3: fp32 out = acc (partial per z)
// Requires M%128==0, N%128==0, kz%64==0, kz >= 128.
// ---------------------------------------------------------------------------
template <int MODE, int SWAP>
__global__ __launch_bounds__(256)
void gemm_bt(const unsigned short* __restrict__ A,
             const unsigned short* __restrict__ Bt,
             void* __restrict__ Cout_v,
             int M, int N, int K, int kz,
             const float* __restrict__ bias,
             const unsigned short* __restrict__ resid) {
    __shared__ __align__(16) unsigned short As[2][128 * 64];
    __shared__ __align__(16) unsigned short Bs[2][128 * 64];

    const int tid = threadIdx.x;
    const int m0 = (SWAP ? blockIdx.x : blockIdx.y) * 128;
    const int n0 = (SWAP ? blockIdx.y : blockIdx.x) * 128;
    const int kbase = blockIdx.z * kz;
    const int wave = tid >> 6, lane = tid & 63;
    const int quad = lane >> 4, l16 = lane & 15;
    const int wm = (wave >> 1) * 64;  // wave row offset in tile
    const int wn = (wave & 1) * 64;   // wave col offset in tile

    f32x4 acc[4][4];
#pragma unroll
    for (int i = 0; i < 4; i++)
#pragma unroll
        for (int j = 0; j < 4; j++) acc[i][j] = (f32x4){0.f, 0.f, 0.f, 0.f};

    // ---- DMA staging addresses -------------------------------------------
    // wave w stages rows [w*32, w*32+32) of A and B as 4 issues of 8 rows
    // each per operand. Lane i covers (row = i>>3, stored slot = i&7); the
    // global chunk it fetches is (i&7) ^ ((i>>3)&7).
    const int rsub = lane >> 3;                   // 0..7
    const int gch = (lane & 7) ^ rsub;            // swizzled global chunk
    const unsigned short* gA = A + (size_t)(m0 + wave * 32 + rsub) * K + kbase + gch * 8;
    const unsigned short* gB = Bt + (size_t)(n0 + wave * 32 + rsub) * K + kbase + gch * 8;
    unsigned short* lA[2] = {&As[0][wave * 32 * 64], &As[1][wave * 32 * 64]};
    unsigned short* lB[2] = {&Bs[0][wave * 32 * 64], &Bs[1][wave * 32 * 64]};

    // prologue: stage tile 0 into buffer 0
#pragma unroll
    for (int j = 0; j < 4; j++) {
        async_copy16(gA + (size_t)j * 8 * K, lA[0] + j * 8 * 64);
        async_copy16(gB + (size_t)j * 8 * K, lB[0] + j * 8 * 64);
    }

    const int swz = l16 & 7;                      // fragment-read swizzle
    int buf = 0;
    for (int k0 = 0; k0 < kz; k0 += 64) {
        __syncthreads();   // drains own-wave DMA (tile k) + all waves' reads of buf^1

        const int nk = k0 + 64;
        if (nk < kz) {     // prefetch tile k+1 into the other buffer
            const int nb = buf ^ 1;
#pragma unroll
            for (int j = 0; j < 4; j++) {
                async_copy16(gA + nk + (size_t)j * 8 * K, lA[nb] + j * 8 * 64);
                async_copy16(gB + nk + (size_t)j * 8 * K, lB[nb] + j * 8 * 64);
            }
        }

        short8 af[2][4], bfr[2][4];
#pragma unroll
        for (int kk = 0; kk < 2; kk++) {
            const int c = kk * 4 + quad;          // global chunk for this kk
#pragma unroll
            for (int i = 0; i < 4; i++) {
                af[kk][i]  = *(const short8*)(&As[buf][(wm + i * 16 + l16) * 64 + (c ^ swz) * 8]);
                bfr[kk][i] = *(const short8*)(&Bs[buf][(wn + i * 16 + l16) * 64 + (c ^ swz) * 8]);
            }
        }
#pragma unroll
        for (int kk = 0; kk < 2; kk++)
#pragma unroll
            for (int mi = 0; mi < 4; mi++)
#pragma unroll
                for (int nj = 0; nj < 4; nj++)
                    acc[mi][nj] = __builtin_amdgcn_mfma_f32_16x16x32_bf16(
                        af[kk][mi], bfr[kk][nj], acc[mi][nj], 0, 0, 0);
        buf ^= 1;
    }

    // epilogue: lane holds D[row=quad*4+i][col=l16] per 16x16 tile
    const int crow0 = m0 + wm + quad * 4;
    const int ccol0 = n0 + wn + l16;
    if (MODE == 3) {
        float* Cf = (float*)Cout_v + (size_t)blockIdx.z * M * N;
#pragma unroll
        for (int mi = 0; mi < 4; mi++)
#pragma unroll
            for (int i = 0; i < 4; i++) {
                int rr = crow0 + mi * 16 + i;
#pragma unroll
                for (int nj = 0; nj < 4; nj++)
                    Cf[(size_t)rr * N + ccol0 + nj * 16] = acc[mi][nj][i];
            }
    } else if (MODE == 1) {
        unsigned short* Cb = (unsigned short*)Cout_v;
        float bv[4];
#pragma unroll
        for (int nj = 0; nj < 4; nj++) bv[nj] = bias[ccol0 + nj * 16];
#pragma unroll
        for (int mi = 0; mi < 4; mi++)
#pragma unroll
            for (int i = 0; i < 4; i++) {
                int rr = crow0 + mi * 16 + i;
#pragma unroll
                for (int nj = 0; nj < 4; nj++) {
                    float v = fmaxf(acc[mi][nj][i] + bv[nj], 0.f);
                    Cb[(size_t)rr * N + ccol0 + nj * 16] = f2bf(v);
                }
            }
    } else {  // MODE 2
        float* Cf = (float*)Cout_v;
        float bv[4];
#pragma unroll
        for (int nj = 0; nj < 4; nj++) bv[nj] = bias[ccol0 + nj * 16];
#pragma unroll
        for (int mi = 0; mi < 4; mi++)
#pragma unroll
            for (int i = 0; i < 4; i++) {
                int rr = crow0 + mi * 16 + i;
#pragma unroll
                for (int nj = 0; nj < 4; nj++) {
                    float v = acc[mi][nj][i] + bv[nj]
                            + bf2f(resid[(size_t)rr * N + ccol0 + nj * 16]);
                    Cf[(size_t)rr * N + ccol0 + nj * 16] = v;
                }
            }
    }
}

// ---------------------------------------------------------------------------
// conv_ln16s: tap-softmax (from 2 split-K wscore partials) + causal dynamic
// conv + LayerNorm, 16 t-rows per block (512 blocks). Phases (all verified in
// rounds 7/8):
//  0) stage 30 xb rows (t0-14 .. t0+15) in LDS, padded stride 1032 elems.
//  1) softmax: 256 threads = 16 rows x 16 heads, sums the 2 global split-K
//     partials + bias, normalizes into LDS.
//  2) conv + LN: wave handles 4 rows, lane owns 16 consecutive channels
//     (head = lane>>2), wave-local shuffle reduction, bf16 y out.
// ---------------------------------------------------------------------------
#define XSP 1032   // padded LDS row stride (bf16 elems)
#define WS_STRIDE ((size_t)TB * 256)
__global__ __launch_bounds__(256)
void conv_ln16s(const unsigned short* __restrict__ xb,
                const float* __restrict__ wscore,
                const float* __restrict__ b_lin,
                const float* __restrict__ ln_g,
                const float* __restrict__ ln_b,
                unsigned short* __restrict__ y) {
    __shared__ __align__(16) unsigned short xs[30 * XSP];   // 60.5 KiB
    __shared__ float wls[16 * 240];                         // 15 KiB
    const int blk = blockIdx.x;          // 0..511
    const int b = blk & 7;
    const int t0 = (blk >> 3) * 16;
    const int tid = threadIdx.x;

    // phase 1 (issue first: independent of x staging): per-(row, head) softmax
    {
        const int row = tid >> 4, hh = tid & 15;
        const size_t grow = (size_t)(t0 + row) * B_DIM + b;
        const float* p = wscore + grow * 256 + hh * K_TAP;
        float v[K_TAP], mx = -1e30f;
#pragma unroll
        for (int k = 0; k < K_TAP; k++) {
            v[k] = p[k] + p[k + WS_STRIDE] + b_lin[hh * K_TAP + k];
            mx = fmaxf(mx, v[k]);
        }
        float s = 0.f;
#pragma unroll
        for (int k = 0; k < K_TAP; k++) { v[k] = __expf(v[k] - mx); s += v[k]; }
        float inv = 1.0f / s;
#pragma unroll
        for (int k = 0; k < K_TAP; k++) wls[row * 240 + hh * K_TAP + k] = v[k] * inv;
    }

    // phase 0: stage 30 x-rows, 8B per thread per row
#pragma unroll
    for (int j = 0; j < 30; j++) {
        int t = t0 + j - 14;
        uint2 val = make_uint2(0u, 0u);
        if (t >= 0)
            val = *(const uint2*)(xb + ((size_t)t * B_DIM + b) * C_DIM + tid * 4);
        *(uint2*)(&xs[j * XSP + tid * 4]) = val;
    }
    __syncthreads();

    // phase 2: conv + LN. wave handles rows wave, wave+4, wave+8, wave+12.
    const int wave = tid >> 6, lane = tid & 63;
    const int ch0 = lane * 16;
    const int h = lane >> 2;             // head index, constant over lane's 16 ch
    for (int rj = wave; rj < 16; rj += 4) {
        float o[16];
#pragma unroll
        for (int i = 0; i < 16; i++) o[i] = 0.f;
#pragma unroll
        for (int k = 0; k < K_TAP; k++) {
            float w = wls[rj * 240 + h * K_TAP + k];
            const unsigned short* xr = &xs[(rj + k) * XSP + ch0];
            uint4 p0 = *(const uint4*)(xr);
            uint4 p1 = *(const uint4*)(xr + 8);
            unsigned int uu[8] = {p0.x, p0.y, p0.z, p0.w, p1.x, p1.y, p1.z, p1.w};
#pragma unroll
            for (int q = 0; q < 8; q++) {
                o[2 * q]     += w * bf2f((unsigned short)(uu[q] & 0xffff));
                o[2 * q + 1] += w * bf2f((unsigned short)(uu[q] >> 16));
            }
        }
        float s = 0.f, s2 = 0.f;
#pragma unroll
        for (int i = 0; i < 16; i++) { s += o[i]; s2 += o[i] * o[i]; }
#pragma unroll
        for (int off = 32; off > 0; off >>= 1) {
            s  += __shfl_xor(s, off, 64);
            s2 += __shfl_xor(s2, off, 64);
        }
        float mu = s * (1.0f / C_DIM);
        float var = s2 * (1.0f / C_DIM) - mu * mu;
        float rs = rsqrtf(var + 1e-5f);

        unsigned short o16[16];
#pragma unroll
        for (int i = 0; i < 16; i++)
            o16[i] = f2bf((o[i] - mu) * rs * ln_g[ch0 + i] + ln_b[ch0 + i]);
        uint4 w0, w1;
        w0.x = (unsigned int)o16[0]  | ((unsigned int)o16[1]  << 16);
        w0.y = (unsigned int)o16[2]  | ((unsigned int)o16[3]  << 16);
        w0.z = (unsigned int)o16[4]  | ((unsigned int)o16[5]  << 16);
        w0.w = (unsigned int)o16[6]  | ((unsigned int)o16[7]  << 16);
        w1.x = (unsigned int)o16[8]  | ((unsigned int)o16[9]  << 16);
        w1.y = (unsigned int)o16[10] | ((unsigned int)o16[11] << 16);
        w1.z = (unsigned int)o16[12] | ((unsigned int)o16[13] << 16);
        w1.w = (unsigned int)o16[14] | ((unsigned int)o16[15] << 16);
        unsigned short* yr = y + ((size_t)(t0 + rj) * B_DIM + b) * C_DIM + ch0;
        *(uint4*)(yr) = w0;
        *(uint4*)(yr + 8) = w1;
    }
}

// ---------------------------------------------------------------------------
extern "C" void kernel_launch(void* const* d_in, const int* in_sizes, int n_in,
                              void* d_out, int out_size, void* d_ws, size_t ws_size,
                              hipStream_t stream) {
    const float* x     = (const float*)d_in[0];
    const float* w_lin = (const float*)d_in[1];
    const float* b_lin = (const float*)d_in[2];
    const float* ln_g  = (const float*)d_in[3];
    const float* ln_b  = (const float*)d_in[4];
    const float* fc1_w = (const float*)d_in[5];
    const float* fc1_b = (const float*)d_in[6];
    const float* fc2_w = (const float*)d_in[7];
    const float* fc2_b = (const float*)d_in[8];
    float* out = (float*)d_out;

    // workspace layout (bytes); total ~112.5 MiB
    char* ws = (char*)d_ws;
    unsigned short* xb    = (unsigned short*)(ws);                      // TB x C   16 MiB
    unsigned short* fc1T  = (unsigned short*)(ws + 16777216);           // F x C     8 MiB
    unsigned short* fc2T  = (unsigned short*)(ws + 25165824);           // C x F     8 MiB
    unsigned short* wlinT = (unsigned short*)(ws + 33554432);           // 256 x C   0.5 MiB
    unsigned short* y     = (unsigned short*)(ws + 34078720);           // TB x C   16 MiB
    unsigned short* h     = (unsigned short*)(ws + 50855936);           // TB x F   64 MiB
    // wscore (2 split-K partials) overlaps h's region (dead before fc1)
    float* wscore = (float*)(ws + 50855936);                            // 2 x TB x 256 fp32 (16 MiB)

    // fused convert + transposes (1 launch)
    prep<<<16640, 256, 0, stream>>>(x, xb, fc1_w, fc1T, fc2_w, fc2T, w_lin, wlinT);

    // conv-weight logits: wscore[z] = xb @ wlinT K-slice (split-K=2, 256 blocks)
    gemm_bt<3, 0><<<dim3(256 / 128, TB / 128, 2), 256, 0, stream>>>(
        xb, wlinT, (void*)wscore, TB, 256, C_DIM, C_DIM / 2, nullptr, nullptr);

    // fused softmax + dynamic conv + LayerNorm -> y (bf16), 16 rows per block
    conv_ln16s<<<TB / 16, 256, 0, stream>>>(xb, wscore, b_lin, ln_g, ln_b, y);

    // h = relu(y @ fc1_w + fc1_b)  (bf16)
    gemm_bt<1, 0><<<dim3(F_DIM / 128, TB / 128, 1), 256, 0, stream>>>(
        y, fc1T, (void*)h, TB, F_DIM, C_DIM, C_DIM, fc1_b, nullptr);

    // out = h @ fc2_w + fc2_b + y  (fp32); m-tile on x for same-XCD h reuse
    gemm_bt<2, 1><<<dim3(TB / 128, C_DIM / 128, 1), 256, 0, stream>>>(
        h, fc2T, (void*)out, TB, C_DIM, F_DIM, F_DIM, fc2_b, y);
}